// Round 6
// baseline (3930.434 us; speedup 1.0000x reference)
//
#include <hip/hip_runtime.h>
#include <stdint.h>

#define DET_THRESH 0.015f

// Zero-cost register-class pin: with the waves_per_eu(2,2) budget below,
// these make AGPR-parking of the accumulators strictly unprofitable.
#define PIN8(A, o) asm volatile("" : "+v"(A[(o)]), "+v"(A[(o)+1]), "+v"(A[(o)+2]), "+v"(A[(o)+3]), \
                                     "+v"(A[(o)+4]), "+v"(A[(o)+5]), "+v"(A[(o)+6]), "+v"(A[(o)+7]))
#define PIN16(A) do { PIN8(A, 0); PIN8(A, 8); } while (0)

// Clamp target occupancy to 2 waves/EU: per-wave arch-VGPR budget = 256,
// so the allocator keeps acc[][] in VGPRs instead of AGPR round-trips
// (accvgpr_read+fma+accvgpr_write = 2.9 VALU/FMA measured in r3-r5).
#define OCC2 __attribute__((amdgpu_waves_per_eu(2, 2)))

// =====================================================================
// Weight pre-transpose: w[co][ci][tap] -> wT[ci*9+tap][co]  (per layer)
// =====================================================================
struct TP {
  const float* src[8];
  float* dst[8];
  int cin[8];
  int cout[8];
};

__global__ __launch_bounds__(256) void k_wT(TP tp) {
  int l = blockIdx.y;
  int n = tp.cin[l] * tp.cout[l] * 9;
  int k = blockIdx.x * 256 + threadIdx.x;
  if (k >= n) return;
  int ci9 = tp.cin[l] * 9;
  int co = k / ci9;
  int r = k - co * ci9;             // r = ci*9 + tap
  tp.dst[l][(size_t)r * tp.cout[l] + co] = tp.src[l][k];
}

// =====================================================================
// Generic 3x3 conv (+bias+relu), optional fused 2x2 maxpool.
// Tile: 32 cols x (8*RT) rows x 16 co. 256 thr = 4 waves.
// Lane: dr = lane>>5, c = lane&31 (stride-1 cols -> conflict-free LDS).
// Thread: RT rows x 1 col x 16 co in VGPR accumulators.
// =====================================================================
template <bool POOL, int RT>
__global__ __launch_bounds__(256) OCC2 void k_conv3(
    const float* __restrict__ in, const float* __restrict__ wT, const float* __restrict__ bias,
    float* __restrict__ out, int CIN, int COUT, int H, int W, int tilesX)
{
  constexpr int ROWS = RT * 8;      // tile rows
  constexpr int SR = ROWS + 2;      // staged rows (halo 1)
  constexpr int CHUNK = 4 * SR * 34;
  __shared__ float ain[4][SR][36];

  int tile = blockIdx.x;
  int tx = tile % tilesX, ty = tile / tilesX;
  int x0 = tx * 32, y0 = ty * ROWS;
  int cob = blockIdx.y * 16;
  int n = blockIdx.z;

  int tid = threadIdx.x;
  int wv = tid >> 6;
  int lane = tid & 63;
  int dr = lane >> 5;
  int c = lane & 31;
  int rb = wv * (2 * RT) + dr * RT;   // local row base

  float acc[RT][16];
#pragma unroll
  for (int k = 0; k < RT; k++)
#pragma unroll
    for (int j = 0; j < 16; j++) acc[k][j] = 0.f;

  int nch = CIN >> 2;
  for (int cc = 0; cc < nch; ++cc) {
    __syncthreads();
    for (int m = tid; m < CHUNK; m += 256) {
      int ci = m / (SR * 34);
      int rem = m - ci * (SR * 34);
      int r = rem / 34;
      int col = rem - r * 34;
      int gy = y0 - 1 + r, gx = x0 - 1 + col;
      float v = 0.f;
      if (gy >= 0 && gy < H && gx >= 0 && gx < W)
        v = in[(((size_t)n * CIN + (cc * 4 + ci)) * H + gy) * W + gx];
      ain[ci][r][col] = v;
    }
    __syncthreads();
#pragma unroll
    for (int ci = 0; ci < 4; ++ci) {
#pragma unroll
      for (int k = 0; k < RT; k++) PIN16(acc[k]);
      float wl[RT + 2], wc[RT + 2], wr[RT + 2];
#pragma unroll
      for (int rr = 0; rr < RT + 2; rr++) {
        wl[rr] = ain[ci][rb + rr][c];
        wc[rr] = ain[ci][rb + rr][c + 1];
        wr[rr] = ain[ci][rb + rr][c + 2];
      }
      const float* wp = wT + (size_t)((cc * 4 + ci) * 9) * COUT + cob;
#pragma unroll
      for (int tap = 0; tap < 9; tap++) {
        const int dy = tap / 3, dx = tap % 3;
        float4 q0 = *(const float4*)(wp + tap * COUT);
        float4 q1 = *(const float4*)(wp + tap * COUT + 4);
        float4 q2 = *(const float4*)(wp + tap * COUT + 8);
        float4 q3 = *(const float4*)(wp + tap * COUT + 12);
#pragma unroll
        for (int k = 0; k < RT; k++) {
          float a = (dx == 0) ? wl[k + dy] : (dx == 1) ? wc[k + dy] : wr[k + dy];
          acc[k][0]  = fmaf(a, q0.x, acc[k][0]);
          acc[k][1]  = fmaf(a, q0.y, acc[k][1]);
          acc[k][2]  = fmaf(a, q0.z, acc[k][2]);
          acc[k][3]  = fmaf(a, q0.w, acc[k][3]);
          acc[k][4]  = fmaf(a, q1.x, acc[k][4]);
          acc[k][5]  = fmaf(a, q1.y, acc[k][5]);
          acc[k][6]  = fmaf(a, q1.z, acc[k][6]);
          acc[k][7]  = fmaf(a, q1.w, acc[k][7]);
          acc[k][8]  = fmaf(a, q2.x, acc[k][8]);
          acc[k][9]  = fmaf(a, q2.y, acc[k][9]);
          acc[k][10] = fmaf(a, q2.z, acc[k][10]);
          acc[k][11] = fmaf(a, q2.w, acc[k][11]);
          acc[k][12] = fmaf(a, q3.x, acc[k][12]);
          acc[k][13] = fmaf(a, q3.y, acc[k][13]);
          acc[k][14] = fmaf(a, q3.z, acc[k][14]);
          acc[k][15] = fmaf(a, q3.w, acc[k][15]);
        }
      }
    }
  }

  float bvv[16];
  {
    const float4* bp = (const float4*)(bias + cob);
    *(float4*)&bvv[0] = bp[0]; *(float4*)&bvv[4] = bp[1];
    *(float4*)&bvv[8] = bp[2]; *(float4*)&bvv[12] = bp[3];
  }
  int x = x0 + c;
  if (!POOL) {
#pragma unroll
    for (int k = 0; k < RT; k++) {
      int y = y0 + rb + k;
      if (y < H && x < W) {
#pragma unroll
        for (int j = 0; j < 16; j++)
          out[(((size_t)n * COUT + cob + j) * H + y) * W + x] = fmaxf(acc[k][j] + bvv[j], 0.f);
      }
    }
  } else {
    int Hp = H >> 1, Wp = W >> 1;
    int pxp = x >> 1;
#pragma unroll
    for (int kp = 0; kp < RT / 2; kp++) {
      int py = (y0 + rb + 2 * kp) >> 1;
      bool ok = ((c & 1) == 0) && (py < Hp) && (x < W);
#pragma unroll
      for (int j = 0; j < 16; j++) {
        float v0 = fmaxf(acc[2 * kp][j] + bvv[j], 0.f);
        float v1 = fmaxf(acc[2 * kp + 1][j] + bvv[j], 0.f);
        float h = fmaxf(v0, v1);
        float m2 = fmaxf(h, __shfl_xor(h, 1, 64));
        if (ok)
          out[(((size_t)n * COUT + cob + j) * Hp + py) * Wp + pxp] = m2;
      }
    }
  }
}

// =====================================================================
// Fused conv0(1->64)+relu -> conv1(64->64)+relu -> 2x2 maxpool.
// =====================================================================
__global__ __launch_bounds__(256) OCC2 void k_f01(
    const float* __restrict__ x, const float* __restrict__ w0g, const float* __restrict__ b0g,
    const float* __restrict__ wT1, const float* __restrict__ b1g, float* __restrict__ out)
{
  const int H = 240, W = 320;
  __shared__ float in_raw[36][38];
  __shared__ float a0[4][34][36];
  __shared__ float w0l[576];
  __shared__ float b0l[64];

  int tile = blockIdx.x;              // tilesX=10, tilesY=8
  int tx = tile % 10, ty = tile / 10;
  int x0 = tx * 32, y0 = ty * 32;
  int cob = blockIdx.y * 16;          // blockIdx.y 0..3
  int n = blockIdx.z;

  int tid = threadIdx.x;
  int wv = tid >> 6;
  int lane = tid & 63;
  int dr = lane >> 5;
  int c = lane & 31;
  int rb = wv * 8 + dr * 4;

  for (int k = tid; k < 576; k += 256) w0l[k] = w0g[k];
  if (tid < 64) b0l[tid] = b0g[tid];
  for (int m = tid; m < 1296; m += 256) {
    int r = m / 36, col = m - r * 36;
    int gy = y0 - 2 + r, gx = x0 - 2 + col;
    in_raw[r][col] = (gy >= 0 && gy < H && gx >= 0 && gx < W)
                         ? x[(size_t)n * (H * W) + gy * W + gx] : 0.f;
  }

  float acc[4][16];
#pragma unroll
  for (int k = 0; k < 4; k++)
#pragma unroll
    for (int j = 0; j < 16; j++) acc[k][j] = 0.f;

  for (int cc = 0; cc < 16; ++cc) {
    __syncthreads();                  // in_raw/w0l ready; a0 free
    // conv0 chunk -> a0 (zero OUTSIDE image: conv1 'SAME' zero-padding)
    for (int m = tid; m < 4624; m += 256) {
      int ch = m / 1156;
      int rem = m - ch * 1156;
      int r = rem / 34;
      int col = rem - r * 34;
      int gy = y0 - 1 + r, gx = x0 - 1 + col;
      float v = 0.f;
      if (gy >= 0 && gy < H && gx >= 0 && gx < W) {
        const float* wp = &w0l[(cc * 4 + ch) * 9];
        float s = b0l[cc * 4 + ch];
#pragma unroll
        for (int dy = 0; dy < 3; dy++)
#pragma unroll
          for (int dx = 0; dx < 3; dx++)
            s = fmaf(in_raw[r + dy][col + dx], wp[dy * 3 + dx], s);
        v = fmaxf(s, 0.f);
      }
      a0[ch][r][col] = v;
    }
    __syncthreads();
#pragma unroll
    for (int ci = 0; ci < 4; ++ci) {
#pragma unroll
      for (int k = 0; k < 4; k++) PIN16(acc[k]);
      float wl[6], wc[6], wr[6];
#pragma unroll
      for (int rr = 0; rr < 6; rr++) {
        wl[rr] = a0[ci][rb + rr][c];
        wc[rr] = a0[ci][rb + rr][c + 1];
        wr[rr] = a0[ci][rb + rr][c + 2];
      }
      const float* wp = wT1 + (size_t)((cc * 4 + ci) * 9) * 64 + cob;
#pragma unroll
      for (int tap = 0; tap < 9; tap++) {
        const int dy = tap / 3, dx = tap % 3;
        float4 q0 = *(const float4*)(wp + tap * 64);
        float4 q1 = *(const float4*)(wp + tap * 64 + 4);
        float4 q2 = *(const float4*)(wp + tap * 64 + 8);
        float4 q3 = *(const float4*)(wp + tap * 64 + 12);
#pragma unroll
        for (int k = 0; k < 4; k++) {
          float a = (dx == 0) ? wl[k + dy] : (dx == 1) ? wc[k + dy] : wr[k + dy];
          acc[k][0]  = fmaf(a, q0.x, acc[k][0]);
          acc[k][1]  = fmaf(a, q0.y, acc[k][1]);
          acc[k][2]  = fmaf(a, q0.z, acc[k][2]);
          acc[k][3]  = fmaf(a, q0.w, acc[k][3]);
          acc[k][4]  = fmaf(a, q1.x, acc[k][4]);
          acc[k][5]  = fmaf(a, q1.y, acc[k][5]);
          acc[k][6]  = fmaf(a, q1.z, acc[k][6]);
          acc[k][7]  = fmaf(a, q1.w, acc[k][7]);
          acc[k][8]  = fmaf(a, q2.x, acc[k][8]);
          acc[k][9]  = fmaf(a, q2.y, acc[k][9]);
          acc[k][10] = fmaf(a, q2.z, acc[k][10]);
          acc[k][11] = fmaf(a, q2.w, acc[k][11]);
          acc[k][12] = fmaf(a, q3.x, acc[k][12]);
          acc[k][13] = fmaf(a, q3.y, acc[k][13]);
          acc[k][14] = fmaf(a, q3.z, acc[k][14]);
          acc[k][15] = fmaf(a, q3.w, acc[k][15]);
        }
      }
    }
  }

  // bias + relu + 2x2 maxpool + store (out: 8,64,120,160)
  float bvv[16];
  {
    const float4* bp = (const float4*)(b1g + cob);
    *(float4*)&bvv[0] = bp[0]; *(float4*)&bvv[4] = bp[1];
    *(float4*)&bvv[8] = bp[2]; *(float4*)&bvv[12] = bp[3];
  }
  int xg = x0 + c;
  int Hp = 120, Wp = 160;
  int pxp = xg >> 1;
#pragma unroll
  for (int kp = 0; kp < 2; kp++) {
    int py = (y0 + rb + 2 * kp) >> 1;
    bool ok = ((c & 1) == 0) && (py < Hp) && (xg < W);
#pragma unroll
    for (int j = 0; j < 16; j++) {
      float v0 = fmaxf(acc[2 * kp][j] + bvv[j], 0.f);
      float v1 = fmaxf(acc[2 * kp + 1][j] + bvv[j], 0.f);
      float h = fmaxf(v0, v1);
      float m2 = fmaxf(h, __shfl_xor(h, 1, 64));
      if (ok)
        out[(((size_t)n * 64 + cob + j) * Hp + py) * Wp + pxp] = m2;
    }
  }
}

// =====================================================================
// Head: conv9 (1x1, 256->65) + bias + softmax(65) + drop dustbin + shuffle
// =====================================================================
__global__ __launch_bounds__(256) OCC2 void k_head(
    const float* __restrict__ act, const float* __restrict__ w9, const float* __restrict__ b9,
    float* __restrict__ prob)
{
  __shared__ float wl[256 * 68];
  int n = blockIdx.y;
  int tid = threadIdx.x;
  for (int k = tid; k < 65 * 256; k += 256) {
    int co = k / 256, ci = k % 256;
    wl[ci * 68 + co] = w9[k];
  }
  for (int ci = tid; ci < 256; ci += 256) {
    wl[ci * 68 + 65] = 0.f; wl[ci * 68 + 66] = 0.f; wl[ci * 68 + 67] = 0.f;
  }
  __syncthreads();
  int px = blockIdx.x * 256 + tid;
  if (px >= 1200) return;

  float accv[68];
#pragma unroll
  for (int i = 0; i < 68; i++) accv[i] = 0.f;

  for (int ci = 0; ci < 256; ++ci) {
    PIN16(accv); PIN8(accv, 16); PIN8(accv, 24);
    PIN16((accv + 32)); PIN16((accv + 48));
    float a = act[((size_t)n * 256 + ci) * 1200 + px];
    const float4* wp = (const float4*)&wl[ci * 68];
#pragma unroll
    for (int g = 0; g < 17; g++) {
      float4 wv = wp[g];
      accv[g * 4 + 0] = fmaf(a, wv.x, accv[g * 4 + 0]);
      accv[g * 4 + 1] = fmaf(a, wv.y, accv[g * 4 + 1]);
      accv[g * 4 + 2] = fmaf(a, wv.z, accv[g * 4 + 2]);
      accv[g * 4 + 3] = fmaf(a, wv.w, accv[g * 4 + 3]);
    }
  }
#pragma unroll
  for (int co = 0; co < 65; co++) accv[co] += b9[co];
  float m = accv[0];
#pragma unroll
  for (int co = 1; co < 65; co++) m = fmaxf(m, accv[co]);
  float s = 0.f;
#pragma unroll
  for (int co = 0; co < 65; co++) { accv[co] = __expf(accv[co] - m); s += accv[co]; }
  float inv = 1.f / s;

  int hc = px / 40, wc = px % 40;
  float* pb = prob + (size_t)n * 76800;
#pragma unroll
  for (int co = 0; co < 64; co++) {
    pb[(hc * 8 + (co >> 3)) * 320 + wc * 8 + (co & 7)] = accv[co] * inv;
  }
}

// =====================================================================
// Exact reference NMS per image.
// =====================================================================
#define MAXC 1024
__global__ __launch_bounds__(1024) void k_nms(
    const float* __restrict__ prob, float* __restrict__ onms, float* __restrict__ opred)
{
  __shared__ unsigned sup[MAXC * 32];
  __shared__ unsigned long long skey[MAXC];
  __shared__ unsigned syx[MAXC];
  __shared__ unsigned hist[256];
  __shared__ unsigned vword[32];
  __shared__ unsigned sh_prefix, sh_K, sh_cG, sh_pG, sh_pE;

  int n = blockIdx.x;
  int tid = threadIdx.x;
  const float* p = prob + (size_t)n * 76800;
  float* on = onms + (size_t)n * 76800;
  float* op = opred + (size_t)n * 76800;

  for (int k = tid; k < 76800; k += 1024) { on[k] = 0.f; op[k] = 0.f; }

  if (tid == 0) { sh_prefix = 0u; sh_K = MAXC; sh_cG = 0u; sh_pG = 0u; sh_pE = 0u; }

  for (int round = 0; round < 4; ++round) {
    if (tid < 256) hist[tid] = 0u;
    __syncthreads();
    unsigned prefix = sh_prefix;
    int shift = 24 - 8 * round;
    unsigned maskHi = (round == 0) ? 0u : (0xFFFFFFFFu << (shift + 8));
    for (int k = tid; k < 76800; k += 1024) {
      unsigned b = __float_as_uint(p[k]);
      if ((b & maskHi) == prefix) atomicAdd(&hist[(b >> shift) & 255], 1u);
    }
    __syncthreads();
    if (tid == 0) {
      unsigned K = sh_K, cum = 0u;
      int bin = 255;
      for (; bin >= 0; --bin) {
        unsigned cgt = hist[bin];
        if (cum + cgt >= K) break;
        cum += cgt;
      }
      sh_prefix = prefix | ((unsigned)bin << shift);
      sh_K = K - cum;
      sh_cG += cum;
    }
    __syncthreads();
  }
  unsigned T = sh_prefix;
  unsigned Kfill = sh_K;
  unsigned Cgt = sh_cG;

  unsigned* eq = sup;
  __syncthreads();
  for (int k = tid; k < 76800; k += 1024) {
    unsigned b = __float_as_uint(p[k]);
    if (b > T) {
      unsigned pos = atomicAdd(&sh_pG, 1u);
      skey[pos] = ((unsigned long long)b << 32) | (unsigned)(~(unsigned)k);
    } else if (b == T) {
      unsigned pos = atomicAdd(&sh_pE, 1u);
      if (pos < 2048u) eq[pos] = (unsigned)k;
    }
  }
  __syncthreads();
  unsigned cE = sh_pE;
  for (int k = tid; k < 2048; k += 1024)
    if ((unsigned)k >= cE) eq[k] = 0xFFFFFFFFu;
  __syncthreads();
  for (int k = 2; k <= 2048; k <<= 1) {
    for (int j = k >> 1; j > 0; j >>= 1) {
      int t = tid;
      int i = ((t & ~(j - 1)) << 1) | (t & (j - 1));
      int l = i | j;
      bool up = ((i & k) == 0);
      unsigned a = eq[i], b2 = eq[l];
      if (up ? (a > b2) : (a < b2)) { eq[i] = b2; eq[l] = a; }
      __syncthreads();
    }
  }
  for (int m2 = tid; m2 < (int)Kfill; m2 += 1024)
    skey[Cgt + m2] = ((unsigned long long)T << 32) | (unsigned)(~eq[m2]);
  __syncthreads();

  for (int k = 2; k <= MAXC; k <<= 1) {
    for (int j = k >> 1; j > 0; j >>= 1) {
      int i = tid;
      int l = i ^ j;
      if (l > i) {
        unsigned long long a = skey[i], b2 = skey[l];
        bool up = ((i & k) == 0);
        if (up ? (a < b2) : (a > b2)) { skey[i] = b2; skey[l] = a; }
      }
      __syncthreads();
    }
  }

  if (tid < 32) vword[tid] = 0u;
  __syncthreads();
  {
    unsigned long long key = skey[tid];
    unsigned vb = (unsigned)(key >> 32);
    float val = __uint_as_float(vb);
    unsigned id = ~(unsigned)key;
    unsigned y = id / 320u, xx = id - 320u * y;
    syx[tid] = (y << 16) | xx;
    if (val > DET_THRESH) atomicOr(&vword[tid >> 5], 1u << (tid & 31));
  }
  __syncthreads();

  {
    unsigned myyx = syx[tid];
    int ty = (int)(myyx >> 16), tx = (int)(myyx & 0xFFFFu);
    for (int w = 0; w < 32; ++w) {
      unsigned bits = 0u;
#pragma unroll 8
      for (int b2 = 0; b2 < 32; ++b2) {
        int j = w * 32 + b2;
        if (j > tid) {
          unsigned o = syx[j];
          int dy = ty - (int)(o >> 16); dy = dy < 0 ? -dy : dy;
          int dx = tx - (int)(o & 0xFFFFu); dx = dx < 0 ? -dx : dx;
          if (((dy | dx) < 4) && (dy + dx) <= 4) bits |= 1u << b2;
        }
      }
      sup[tid * 32 + w] = bits;
    }
  }
  __syncthreads();

  if (tid < 64) {
    int lw = tid;
    unsigned keepw = (lw < 32) ? vword[lw] : 0u;
    for (int i = 0; i < MAXC; ++i) {
      unsigned kword = __shfl(keepw, i >> 5, 64);
      if ((kword >> (i & 31)) & 1u) {
        if (lw < 32) keepw &= ~sup[i * 32 + lw];
      }
    }
    unsigned pc = (lw < 32) ? (unsigned)__builtin_popcount(keepw) : 0u;
    unsigned incl = pc;
    for (int d = 1; d < 32; d <<= 1) {
      unsigned t2 = __shfl_up(incl, d, 64);
      if (lw >= d) incl += t2;
    }
    unsigned excl = incl - pc;
    if (lw < 32) {
      int quota = 300 - (int)excl;
      if (quota <= 0) keepw = 0u;
      else if ((int)pc > quota) {
        while (__builtin_popcount(keepw) > quota)
          keepw &= ~(1u << (31 - __builtin_clz(keepw)));
      }
      unsigned kw = keepw;
      while (kw) {
        int b2 = __builtin_ffs((int)kw) - 1;
        kw &= kw - 1u;
        int i = lw * 32 + b2;
        unsigned long long key = skey[i];
        float v = __uint_as_float((unsigned)(key >> 32));
        unsigned id = ~(unsigned)key;
        on[id] = v;
        op[id] = v;
      }
    }
  }
}

// =====================================================================
extern "C" void kernel_launch(void* const* d_in, const int* in_sizes, int n_in,
                              void* d_out, int out_size, void* d_ws, size_t ws_size,
                              hipStream_t stream) {
  const float* x = (const float*)d_in[0];
  const float* w[10];
  const float* b[10];
  for (int i = 0; i < 10; ++i) {
    w[i] = (const float*)d_in[1 + 2 * i];
    b[i] = (const float*)d_in[2 + 2 * i];
  }
  float* A = (float*)d_ws;
  float* B = A + 9830400;        // 64*120*160*8
  float* prob  = (float*)d_out;
  float* onms  = prob + 614400;  // 8*240*320
  float* opred = onms + 614400;

  // Transposed weights live in the onms/opred region (dead until k_nms,
  // which rewrites it entirely). Total 921600 floats <= 1228800 available.
  float* wT1 = onms;
  float* wT2 = wT1 + 36864;
  float* wT3 = wT2 + 36864;
  float* wT4 = wT3 + 36864;
  float* wT5 = wT4 + 73728;
  float* wT6 = wT5 + 147456;
  float* wT7 = wT6 + 147456;
  float* wT8 = wT7 + 147456;

  TP tp;
  tp.src[0] = w[1]; tp.dst[0] = wT1; tp.cin[0] = 64;  tp.cout[0] = 64;
  tp.src[1] = w[2]; tp.dst[1] = wT2; tp.cin[1] = 64;  tp.cout[1] = 64;
  tp.src[2] = w[3]; tp.dst[2] = wT3; tp.cin[2] = 64;  tp.cout[2] = 64;
  tp.src[3] = w[4]; tp.dst[3] = wT4; tp.cin[3] = 64;  tp.cout[3] = 128;
  tp.src[4] = w[5]; tp.dst[4] = wT5; tp.cin[4] = 128; tp.cout[4] = 128;
  tp.src[5] = w[6]; tp.dst[5] = wT6; tp.cin[5] = 128; tp.cout[5] = 128;
  tp.src[6] = w[7]; tp.dst[6] = wT7; tp.cin[6] = 128; tp.cout[6] = 128;
  tp.src[7] = w[8]; tp.dst[7] = wT8; tp.cin[7] = 128; tp.cout[7] = 256;
  k_wT<<<dim3(1152, 8), 256, 0, stream>>>(tp);

  // conv0+conv1+pool -> A (8,64,120,160). tiles 10x8, co-blocks 4.
  k_f01<<<dim3(80, 4, 8), 256, 0, stream>>>(x, w[0], b[0], wT1, b[1], A);
  // conv2 -> B (8,64,120,160). tiles 5x4.
  k_conv3<false, 4><<<dim3(20, 4, 8), 256, 0, stream>>>(A, wT2, b[2], B, 64, 64, 120, 160, 5);
  // conv3+pool -> A (8,64,60,80)
  k_conv3<true, 4><<<dim3(20, 4, 8), 256, 0, stream>>>(B, wT3, b[3], A, 64, 64, 120, 160, 5);
  // conv4 -> B (8,128,60,80). tiles 3x2.
  k_conv3<false, 4><<<dim3(6, 8, 8), 256, 0, stream>>>(A, wT4, b[4], B, 64, 128, 60, 80, 3);
  // conv5+pool -> A (8,128,30,40)
  k_conv3<true, 4><<<dim3(6, 8, 8), 256, 0, stream>>>(B, wT5, b[5], A, 128, 128, 60, 80, 3);
  // conv6 -> B. RT=2: tiles 2x2 -> 256 blocks.
  k_conv3<false, 2><<<dim3(4, 8, 8), 256, 0, stream>>>(A, wT6, b[6], B, 128, 128, 30, 40, 2);
  // conv7 -> A
  k_conv3<false, 2><<<dim3(4, 8, 8), 256, 0, stream>>>(B, wT7, b[7], A, 128, 128, 30, 40, 2);
  // conv8 -> B (8,256,30,40)
  k_conv3<false, 2><<<dim3(4, 16, 8), 256, 0, stream>>>(A, wT8, b[8], B, 128, 256, 30, 40, 2);
  // convPb + softmax + shuffle -> prob
  k_head<<<dim3(5, 8), 256, 0, stream>>>(B, w[9], b[9], prob);
  // NMS + top-300 -> prob_nms, pred (rewrites the wT region)
  k_nms<<<dim3(8), 1024, 0, stream>>>(prob, onms, opred);
}

// Round 7
// 2312.425 us; speedup vs baseline: 1.6997x; 1.6997x over previous
//
#include <hip/hip_runtime.h>
#include <stdint.h>

#define DET_THRESH 0.015f

// =====================================================================
// Weight pre-transpose: w[co][ci][tap] -> wT[ci*9+tap][co]  (per layer)
// =====================================================================
struct TP {
  const float* src[8];
  float* dst[8];
  int cin[8];
  int cout[8];
};

__global__ __launch_bounds__(256) void k_wT(TP tp) {
  int l = blockIdx.y;
  int n = tp.cin[l] * tp.cout[l] * 9;
  int k = blockIdx.x * 256 + threadIdx.x;
  if (k >= n) return;
  int ci9 = tp.cin[l] * 9;
  int co = k / ci9;
  int r = k - co * ci9;             // r = ci*9 + tap
  tp.dst[l][(size_t)r * tp.cout[l] + co] = tp.src[l][k];
}

// =====================================================================
// Generic 3x3 conv (+bias+relu), optional fused 2x2 maxpool.
// Tile: 32 cols x 8 rows x 16 co. 256 thr: r=tid>>5 (0..7), c=tid&31.
// Thread: 1 row x 1 col x 16 co -> acc[16] (+ window 9 + addr ~ 45-55
// VGPR total: small enough that the allocator never touches AGPRs --
// the 64-acc variant burned 2.7 VALU inst/FMA on accvgpr round-trips).
// Weights: wave-uniform s_load from pre-transposed wT.
// =====================================================================
template <bool POOL>
__global__ __launch_bounds__(256) void k_conv(
    const float* __restrict__ in, const float* __restrict__ wT, const float* __restrict__ bias,
    float* __restrict__ out, int CIN, int COUT, int H, int W, int tilesX)
{
  __shared__ float ain[4][10][36];   // 4 ci x (8+2) rows x (32+2 pad->36) cols

  int tile = blockIdx.x;
  int tx = tile % tilesX, ty = tile / tilesX;
  int x0 = tx * 32, y0 = ty * 8;
  int cob = blockIdx.y * 16;
  int n = blockIdx.z;

  int tid = threadIdx.x;
  int r = tid >> 5;
  int c = tid & 31;

  float acc[16];
#pragma unroll
  for (int j = 0; j < 16; j++) acc[j] = 0.f;

  int nch = CIN >> 2;
  for (int cc = 0; cc < nch; ++cc) {
    __syncthreads();
    // stage 4 ci x 10 x 34 = 1360 words (lane-consecutive cols)
    for (int m = tid; m < 1360; m += 256) {
      int ci = m / 340;
      int rem = m - ci * 340;
      int rr = rem / 34;
      int col = rem - rr * 34;
      int gy = y0 - 1 + rr, gx = x0 - 1 + col;
      float v = 0.f;
      if (gy >= 0 && gy < H && gx >= 0 && gx < W)
        v = in[(((size_t)n * CIN + (cc * 4 + ci)) * H + gy) * W + gx];
      ain[ci][rr][col] = v;
    }
    __syncthreads();
#pragma unroll
    for (int ci = 0; ci < 4; ++ci) {
      float win[3][3];
#pragma unroll
      for (int dy = 0; dy < 3; dy++) {
        win[dy][0] = ain[ci][r + dy][c];
        win[dy][1] = ain[ci][r + dy][c + 1];
        win[dy][2] = ain[ci][r + dy][c + 2];
      }
      const float* wp = wT + (size_t)((cc * 4 + ci) * 9) * COUT + cob;
#pragma unroll
      for (int tap = 0; tap < 9; tap++) {
        float4 q0 = *(const float4*)(wp + tap * COUT);
        float4 q1 = *(const float4*)(wp + tap * COUT + 4);
        float4 q2 = *(const float4*)(wp + tap * COUT + 8);
        float4 q3 = *(const float4*)(wp + tap * COUT + 12);
        float a = win[tap / 3][tap % 3];
        acc[0]  = fmaf(a, q0.x, acc[0]);
        acc[1]  = fmaf(a, q0.y, acc[1]);
        acc[2]  = fmaf(a, q0.z, acc[2]);
        acc[3]  = fmaf(a, q0.w, acc[3]);
        acc[4]  = fmaf(a, q1.x, acc[4]);
        acc[5]  = fmaf(a, q1.y, acc[5]);
        acc[6]  = fmaf(a, q1.z, acc[6]);
        acc[7]  = fmaf(a, q1.w, acc[7]);
        acc[8]  = fmaf(a, q2.x, acc[8]);
        acc[9]  = fmaf(a, q2.y, acc[9]);
        acc[10] = fmaf(a, q2.z, acc[10]);
        acc[11] = fmaf(a, q2.w, acc[11]);
        acc[12] = fmaf(a, q3.x, acc[12]);
        acc[13] = fmaf(a, q3.y, acc[13]);
        acc[14] = fmaf(a, q3.z, acc[14]);
        acc[15] = fmaf(a, q3.w, acc[15]);
      }
    }
  }

  float bvv[16];
  {
    const float4* bp = (const float4*)(bias + cob);
    *(float4*)&bvv[0] = bp[0]; *(float4*)&bvv[4] = bp[1];
    *(float4*)&bvv[8] = bp[2]; *(float4*)&bvv[12] = bp[3];
  }
  int x = x0 + c;
  int y = y0 + r;
  if (!POOL) {
    if (y < H && x < W) {
#pragma unroll
      for (int j = 0; j < 16; j++)
        out[(((size_t)n * COUT + cob + j) * H + y) * W + x] = fmaxf(acc[j] + bvv[j], 0.f);
    }
  } else {
    // rows pair across lane^32 (r even/odd), cols pair across lane^1
    int Hp = H >> 1, Wp = W >> 1;
    int py = y >> 1, pxp = x >> 1;
    bool ok = ((r & 1) == 0) && ((c & 1) == 0) && (py < Hp) && (pxp < Wp);
#pragma unroll
    for (int j = 0; j < 16; j++) {
      float h = fmaxf(acc[j] + bvv[j], 0.f);
      float hc = fmaxf(h, __shfl_xor(h, 1, 64));    // col pair
      float hv = fmaxf(hc, __shfl_xor(hc, 32, 64)); // row pair
      if (ok)
        out[(((size_t)n * COUT + cob + j) * Hp + py) * Wp + pxp] = hv;
    }
  }
}

// =====================================================================
// Fused conv0(1->64)+relu -> conv1(64->64)+relu -> 2x2 maxpool.
// Same 32x8x16 geometry; conv0 recomputed per 4-channel chunk into LDS.
// =====================================================================
__global__ __launch_bounds__(256) void k_f01(
    const float* __restrict__ x, const float* __restrict__ w0g, const float* __restrict__ b0g,
    const float* __restrict__ wT1, const float* __restrict__ b1g, float* __restrict__ out)
{
  const int H = 240, W = 320;
  __shared__ float in_raw[12][36];
  __shared__ float a0[4][10][36];
  __shared__ float w0l[576];
  __shared__ float b0l[64];

  int tile = blockIdx.x;              // tilesX=10, tilesY=30
  int tx = tile % 10, ty = tile / 10;
  int x0 = tx * 32, y0 = ty * 8;
  int cob = blockIdx.y * 16;          // 0..3
  int n = blockIdx.z;

  int tid = threadIdx.x;
  int r = tid >> 5;
  int c = tid & 31;

  for (int k = tid; k < 576; k += 256) w0l[k] = w0g[k];
  if (tid < 64) b0l[tid] = b0g[tid];
  for (int m = tid; m < 432; m += 256) {
    int rr = m / 36, col = m - rr * 36;
    int gy = y0 - 2 + rr, gx = x0 - 2 + col;
    in_raw[rr][col] = (gy >= 0 && gy < H && gx >= 0 && gx < W)
                          ? x[(size_t)n * (H * W) + gy * W + gx] : 0.f;
  }

  float acc[16];
#pragma unroll
  for (int j = 0; j < 16; j++) acc[j] = 0.f;

  for (int cc = 0; cc < 16; ++cc) {
    __syncthreads();                  // in_raw/w0l ready; a0 free
    // conv0 chunk -> a0 (zero OUTSIDE image: conv1 'SAME' zero-padding)
    for (int m = tid; m < 1360; m += 256) {
      int ch = m / 340;
      int rem = m - ch * 340;
      int rr = rem / 34;
      int col = rem - rr * 34;
      int gy = y0 - 1 + rr, gx = x0 - 1 + col;
      float v = 0.f;
      if (gy >= 0 && gy < H && gx >= 0 && gx < W) {
        const float* wp = &w0l[(cc * 4 + ch) * 9];
        float s = b0l[cc * 4 + ch];
#pragma unroll
        for (int dy = 0; dy < 3; dy++)
#pragma unroll
          for (int dx = 0; dx < 3; dx++)
            s = fmaf(in_raw[rr + dy][col + dx], wp[dy * 3 + dx], s);
        v = fmaxf(s, 0.f);
      }
      a0[ch][rr][col] = v;
    }
    __syncthreads();
#pragma unroll
    for (int ci = 0; ci < 4; ++ci) {
      float win[3][3];
#pragma unroll
      for (int dy = 0; dy < 3; dy++) {
        win[dy][0] = a0[ci][r + dy][c];
        win[dy][1] = a0[ci][r + dy][c + 1];
        win[dy][2] = a0[ci][r + dy][c + 2];
      }
      const float* wp = wT1 + (size_t)((cc * 4 + ci) * 9) * 64 + cob;
#pragma unroll
      for (int tap = 0; tap < 9; tap++) {
        float4 q0 = *(const float4*)(wp + tap * 64);
        float4 q1 = *(const float4*)(wp + tap * 64 + 4);
        float4 q2 = *(const float4*)(wp + tap * 64 + 8);
        float4 q3 = *(const float4*)(wp + tap * 64 + 12);
        float a = win[tap / 3][tap % 3];
        acc[0]  = fmaf(a, q0.x, acc[0]);
        acc[1]  = fmaf(a, q0.y, acc[1]);
        acc[2]  = fmaf(a, q0.z, acc[2]);
        acc[3]  = fmaf(a, q0.w, acc[3]);
        acc[4]  = fmaf(a, q1.x, acc[4]);
        acc[5]  = fmaf(a, q1.y, acc[5]);
        acc[6]  = fmaf(a, q1.z, acc[6]);
        acc[7]  = fmaf(a, q1.w, acc[7]);
        acc[8]  = fmaf(a, q2.x, acc[8]);
        acc[9]  = fmaf(a, q2.y, acc[9]);
        acc[10] = fmaf(a, q2.z, acc[10]);
        acc[11] = fmaf(a, q2.w, acc[11]);
        acc[12] = fmaf(a, q3.x, acc[12]);
        acc[13] = fmaf(a, q3.y, acc[13]);
        acc[14] = fmaf(a, q3.z, acc[14]);
        acc[15] = fmaf(a, q3.w, acc[15]);
      }
    }
  }

  // bias + relu + 2x2 maxpool + store (out: 8,64,120,160)
  float bvv[16];
  {
    const float4* bp = (const float4*)(b1g + cob);
    *(float4*)&bvv[0] = bp[0]; *(float4*)&bvv[4] = bp[1];
    *(float4*)&bvv[8] = bp[2]; *(float4*)&bvv[12] = bp[3];
  }
  int Hp = 120, Wp = 160;
  int py = (y0 + r) >> 1, pxp = (x0 + c) >> 1;
  bool ok = ((r & 1) == 0) && ((c & 1) == 0);
#pragma unroll
  for (int j = 0; j < 16; j++) {
    float h = fmaxf(acc[j] + bvv[j], 0.f);
    float hc = fmaxf(h, __shfl_xor(h, 1, 64));
    float hv = fmaxf(hc, __shfl_xor(hc, 32, 64));
    if (ok)
      out[(((size_t)n * 64 + cob + j) * Hp + py) * Wp + pxp] = hv;
  }
}

// =====================================================================
// Head: conv9 (1x1, 256->65) + bias + softmax(65) + drop dustbin + shuffle
// 2-lane teams: even lane co 0..33, odd lane co 34..64 (34/31 accs each,
// no AGPR pressure). 256 thr -> 128 pixels/block.
// =====================================================================
__global__ __launch_bounds__(256) void k_head(
    const float* __restrict__ act, const float* __restrict__ w9, const float* __restrict__ b9,
    float* __restrict__ prob)
{
  __shared__ float wl[256 * 68];
  int n = blockIdx.y;
  int tid = threadIdx.x;
  for (int k = tid; k < 65 * 256; k += 256) {
    int co = k / 256, ci = k % 256;
    wl[ci * 68 + co] = w9[k];
  }
  for (int ci = tid; ci < 256; ci += 256) {
    wl[ci * 68 + 65] = 0.f; wl[ci * 68 + 66] = 0.f; wl[ci * 68 + 67] = 0.f;
  }
  __syncthreads();
  int px = blockIdx.x * 128 + (tid >> 1);
  int half = tid & 1;
  bool live = (px < 1200);
  int cbase = half * 34;
  int nreal = half ? 31 : 34;    // real co count (incl. dustbin 64 on odd)

  float accv[34];
#pragma unroll
  for (int i = 0; i < 34; i++) accv[i] = 0.f;

  if (live) {
    for (int ci = 0; ci < 256; ++ci) {
      float a = act[((size_t)n * 256 + ci) * 1200 + px];
      const float2* wp = (const float2*)&wl[ci * 68 + cbase];
#pragma unroll
      for (int g = 0; g < 17; g++) {
        float2 wv = wp[g];
        accv[g * 2 + 0] = fmaf(a, wv.x, accv[g * 2 + 0]);
        accv[g * 2 + 1] = fmaf(a, wv.y, accv[g * 2 + 1]);
      }
    }
  }
  // bias + softmax across the lane pair
  for (int i = 0; i < 34; i++)
    if (i < nreal) accv[i] += b9[cbase + i];
  float m = -1e30f;
  for (int i = 0; i < 34; i++)
    if (i < nreal) m = fmaxf(m, accv[i]);
  m = fmaxf(m, __shfl_xor(m, 1, 64));
  float s = 0.f;
  for (int i = 0; i < 34; i++)
    if (i < nreal) { accv[i] = __expf(accv[i] - m); s += accv[i]; }
  s += __shfl_xor(s, 1, 64);
  float inv = 1.f / s;

  if (live) {
    int hc = px / 40, wc = px % 40;
    float* pb = prob + (size_t)n * 76800;
    int nw = half ? 30 : 34;     // write only co < 64
    for (int i = 0; i < nw; i++) {
      int co = cbase + i;
      pb[(hc * 8 + (co >> 3)) * 320 + wc * 8 + (co & 7)] = accv[i] * inv;
    }
  }
}

// =====================================================================
// Exact reference NMS per image.
// =====================================================================
#define MAXC 1024
__global__ __launch_bounds__(1024) void k_nms(
    const float* __restrict__ prob, float* __restrict__ onms, float* __restrict__ opred)
{
  __shared__ unsigned sup[MAXC * 32];
  __shared__ unsigned long long skey[MAXC];
  __shared__ unsigned syx[MAXC];
  __shared__ unsigned hist[256];
  __shared__ unsigned vword[32];
  __shared__ unsigned sh_prefix, sh_K, sh_cG, sh_pG, sh_pE;

  int n = blockIdx.x;
  int tid = threadIdx.x;
  const float* p = prob + (size_t)n * 76800;
  float* on = onms + (size_t)n * 76800;
  float* op = opred + (size_t)n * 76800;

  for (int k = tid; k < 76800; k += 1024) { on[k] = 0.f; op[k] = 0.f; }

  if (tid == 0) { sh_prefix = 0u; sh_K = MAXC; sh_cG = 0u; sh_pG = 0u; sh_pE = 0u; }

  for (int round = 0; round < 4; ++round) {
    if (tid < 256) hist[tid] = 0u;
    __syncthreads();
    unsigned prefix = sh_prefix;
    int shift = 24 - 8 * round;
    unsigned maskHi = (round == 0) ? 0u : (0xFFFFFFFFu << (shift + 8));
    for (int k = tid; k < 76800; k += 1024) {
      unsigned b = __float_as_uint(p[k]);
      if ((b & maskHi) == prefix) atomicAdd(&hist[(b >> shift) & 255], 1u);
    }
    __syncthreads();
    if (tid == 0) {
      unsigned K = sh_K, cum = 0u;
      int bin = 255;
      for (; bin >= 0; --bin) {
        unsigned cgt = hist[bin];
        if (cum + cgt >= K) break;
        cum += cgt;
      }
      sh_prefix = prefix | ((unsigned)bin << shift);
      sh_K = K - cum;
      sh_cG += cum;
    }
    __syncthreads();
  }
  unsigned T = sh_prefix;
  unsigned Kfill = sh_K;
  unsigned Cgt = sh_cG;

  unsigned* eq = sup;
  __syncthreads();
  for (int k = tid; k < 76800; k += 1024) {
    unsigned b = __float_as_uint(p[k]);
    if (b > T) {
      unsigned pos = atomicAdd(&sh_pG, 1u);
      skey[pos] = ((unsigned long long)b << 32) | (unsigned)(~(unsigned)k);
    } else if (b == T) {
      unsigned pos = atomicAdd(&sh_pE, 1u);
      if (pos < 2048u) eq[pos] = (unsigned)k;
    }
  }
  __syncthreads();
  unsigned cE = sh_pE;
  for (int k = tid; k < 2048; k += 1024)
    if ((unsigned)k >= cE) eq[k] = 0xFFFFFFFFu;
  __syncthreads();
  for (int k = 2; k <= 2048; k <<= 1) {
    for (int j = k >> 1; j > 0; j >>= 1) {
      int t = tid;
      int i = ((t & ~(j - 1)) << 1) | (t & (j - 1));
      int l = i | j;
      bool up = ((i & k) == 0);
      unsigned a = eq[i], b2 = eq[l];
      if (up ? (a > b2) : (a < b2)) { eq[i] = b2; eq[l] = a; }
      __syncthreads();
    }
  }
  for (int m2 = tid; m2 < (int)Kfill; m2 += 1024)
    skey[Cgt + m2] = ((unsigned long long)T << 32) | (unsigned)(~eq[m2]);
  __syncthreads();

  for (int k = 2; k <= MAXC; k <<= 1) {
    for (int j = k >> 1; j > 0; j >>= 1) {
      int i = tid;
      int l = i ^ j;
      if (l > i) {
        unsigned long long a = skey[i], b2 = skey[l];
        bool up = ((i & k) == 0);
        if (up ? (a < b2) : (a > b2)) { skey[i] = b2; skey[l] = a; }
      }
      __syncthreads();
    }
  }

  if (tid < 32) vword[tid] = 0u;
  __syncthreads();
  {
    unsigned long long key = skey[tid];
    unsigned vb = (unsigned)(key >> 32);
    float val = __uint_as_float(vb);
    unsigned id = ~(unsigned)key;
    unsigned y = id / 320u, xx = id - 320u * y;
    syx[tid] = (y << 16) | xx;
    if (val > DET_THRESH) atomicOr(&vword[tid >> 5], 1u << (tid & 31));
  }
  __syncthreads();

  {
    unsigned myyx = syx[tid];
    int ty = (int)(myyx >> 16), tx = (int)(myyx & 0xFFFFu);
    for (int w = 0; w < 32; ++w) {
      unsigned bits = 0u;
#pragma unroll 8
      for (int b2 = 0; b2 < 32; ++b2) {
        int j = w * 32 + b2;
        if (j > tid) {
          unsigned o = syx[j];
          int dy = ty - (int)(o >> 16); dy = dy < 0 ? -dy : dy;
          int dx = tx - (int)(o & 0xFFFFu); dx = dx < 0 ? -dx : dx;
          if (((dy | dx) < 4) && (dy + dx) <= 4) bits |= 1u << b2;
        }
      }
      sup[tid * 32 + w] = bits;
    }
  }
  __syncthreads();

  if (tid < 64) {
    int lw = tid;
    unsigned keepw = (lw < 32) ? vword[lw] : 0u;
    for (int i = 0; i < MAXC; ++i) {
      unsigned kword = __shfl(keepw, i >> 5, 64);
      if ((kword >> (i & 31)) & 1u) {
        if (lw < 32) keepw &= ~sup[i * 32 + lw];
      }
    }
    unsigned pc = (lw < 32) ? (unsigned)__builtin_popcount(keepw) : 0u;
    unsigned incl = pc;
    for (int d = 1; d < 32; d <<= 1) {
      unsigned t2 = __shfl_up(incl, d, 64);
      if (lw >= d) incl += t2;
    }
    unsigned excl = incl - pc;
    if (lw < 32) {
      int quota = 300 - (int)excl;
      if (quota <= 0) keepw = 0u;
      else if ((int)pc > quota) {
        while (__builtin_popcount(keepw) > quota)
          keepw &= ~(1u << (31 - __builtin_clz(keepw)));
      }
      unsigned kw = keepw;
      while (kw) {
        int b2 = __builtin_ffs((int)kw) - 1;
        kw &= kw - 1u;
        int i = lw * 32 + b2;
        unsigned long long key = skey[i];
        float v = __uint_as_float((unsigned)(key >> 32));
        unsigned id = ~(unsigned)key;
        on[id] = v;
        op[id] = v;
      }
    }
  }
}

// =====================================================================
extern "C" void kernel_launch(void* const* d_in, const int* in_sizes, int n_in,
                              void* d_out, int out_size, void* d_ws, size_t ws_size,
                              hipStream_t stream) {
  const float* x = (const float*)d_in[0];
  const float* w[10];
  const float* b[10];
  for (int i = 0; i < 10; ++i) {
    w[i] = (const float*)d_in[1 + 2 * i];
    b[i] = (const float*)d_in[2 + 2 * i];
  }
  float* A = (float*)d_ws;
  float* B = A + 9830400;        // 64*120*160*8
  float* prob  = (float*)d_out;
  float* onms  = prob + 614400;  // 8*240*320
  float* opred = onms + 614400;

  // Transposed weights live in the onms/opred region (dead until k_nms,
  // which rewrites it entirely). Total 921600 floats <= 1228800 available.
  float* wT1 = onms;
  float* wT2 = wT1 + 36864;
  float* wT3 = wT2 + 36864;
  float* wT4 = wT3 + 36864;
  float* wT5 = wT4 + 73728;
  float* wT6 = wT5 + 147456;
  float* wT7 = wT6 + 147456;
  float* wT8 = wT7 + 147456;

  TP tp;
  tp.src[0] = w[1]; tp.dst[0] = wT1; tp.cin[0] = 64;  tp.cout[0] = 64;
  tp.src[1] = w[2]; tp.dst[1] = wT2; tp.cin[1] = 64;  tp.cout[1] = 64;
  tp.src[2] = w[3]; tp.dst[2] = wT3; tp.cin[2] = 64;  tp.cout[2] = 64;
  tp.src[3] = w[4]; tp.dst[3] = wT4; tp.cin[3] = 64;  tp.cout[3] = 128;
  tp.src[4] = w[5]; tp.dst[4] = wT5; tp.cin[4] = 128; tp.cout[4] = 128;
  tp.src[5] = w[6]; tp.dst[5] = wT6; tp.cin[5] = 128; tp.cout[5] = 128;
  tp.src[6] = w[7]; tp.dst[6] = wT7; tp.cin[6] = 128; tp.cout[6] = 128;
  tp.src[7] = w[8]; tp.dst[7] = wT8; tp.cin[7] = 128; tp.cout[7] = 256;
  k_wT<<<dim3(1152, 8), 256, 0, stream>>>(tp);

  // conv0+conv1+pool -> A (8,64,120,160). tiles 10x30.
  k_f01<<<dim3(300, 4, 8), 256, 0, stream>>>(x, w[0], b[0], wT1, b[1], A);
  // conv2 -> B (8,64,120,160). tiles 5x15.
  k_conv<false><<<dim3(75, 4, 8), 256, 0, stream>>>(A, wT2, b[2], B, 64, 64, 120, 160, 5);
  // conv3+pool -> A (8,64,60,80)
  k_conv<true ><<<dim3(75, 4, 8), 256, 0, stream>>>(B, wT3, b[3], A, 64, 64, 120, 160, 5);
  // conv4 -> B (8,128,60,80). tiles 3x8.
  k_conv<false><<<dim3(24, 8, 8), 256, 0, stream>>>(A, wT4, b[4], B, 64, 128, 60, 80, 3);
  // conv5+pool -> A (8,128,30,40)
  k_conv<true ><<<dim3(24, 8, 8), 256, 0, stream>>>(B, wT5, b[5], A, 128, 128, 60, 80, 3);
  // conv6 -> B (8,128,30,40). tiles 2x4.
  k_conv<false><<<dim3(8, 8, 8), 256, 0, stream>>>(A, wT6, b[6], B, 128, 128, 30, 40, 2);
  // conv7 -> A
  k_conv<false><<<dim3(8, 8, 8), 256, 0, stream>>>(B, wT7, b[7], A, 128, 128, 30, 40, 2);
  // conv8 -> B (8,256,30,40)
  k_conv<false><<<dim3(8, 16, 8), 256, 0, stream>>>(A, wT8, b[8], B, 128, 256, 30, 40, 2);
  // convPb + softmax + shuffle -> prob. 10 blocks x 128 px.
  k_head<<<dim3(10, 8), 256, 0, stream>>>(B, w[9], b[9], prob);
  // NMS + top-300 -> prob_nms, pred (rewrites the wT region)
  k_nms<<<dim3(8), 1024, 0, stream>>>(prob, onms, opred);
}